// Round 6
// baseline (547.442 us; speedup 1.0000x reference)
//
#include <hip/hip_runtime.h>
#include <hip/hip_fp16.h>

#define BSZ 1024   // B
#define VSZ 4096   // V
#define NBLK 64    // sinkhorn blocks
#define KPAD 1040  // LDS row stride for K (1024 + 16 floats)

typedef _Float16 h2 __attribute__((ext_vector_type(2)));
union F4H { float4 f; h2 h[4]; };

#if defined(__has_builtin) && __has_builtin(__builtin_elementwise_min)
#define H2MIN(a, b) __builtin_elementwise_min((a), (b))
#else
static __device__ inline h2 H2MIN(h2 a, h2 b) {
    h2 r; r[0] = a[0] < b[0] ? a[0] : b[0]; r[1] = a[1] < b[1] ? a[1] : b[1]; return r;
}
#endif

// ---------------- softmax(y/2) row-wise, writes f16 probs ---------------------
__global__ __launch_bounds__(256) void softmax_kernel(const float* __restrict__ ys,
                                                      const float* __restrict__ yt,
                                                      __half* __restrict__ ps,
                                                      __half* __restrict__ pt) {
    int row = blockIdx.x;
    const float* src;
    __half* dst;
    if (row < BSZ) { src = ys + (size_t)row * VSZ;         dst = ps + (size_t)row * VSZ; }
    else           { src = yt + (size_t)(row - BSZ) * VSZ; dst = pt + (size_t)(row - BSZ) * VSZ; }
    int t = threadIdx.x;
    float4 v[4];
    float m = -1e30f;
#pragma unroll
    for (int k = 0; k < 4; ++k) {
        v[k] = ((const float4*)src)[t + 256 * k];
        m = fmaxf(m, fmaxf(fmaxf(v[k].x, v[k].y), fmaxf(v[k].z, v[k].w)));
    }
#pragma unroll
    for (int d = 32; d >= 1; d >>= 1) m = fmaxf(m, __shfl_down(m, d));
    __shared__ float sred[4];
    __shared__ float sred2[4];
    int lane = t & 63, wid = t >> 6;
    if (lane == 0) sred[wid] = m;
    __syncthreads();
    m = fmaxf(fmaxf(sred[0], sred[1]), fmaxf(sred[2], sred[3]));
    const float C = 0.7213475204444817f;  // 0.5 * log2(e)  (T = 2)
    float s = 0.f;
#pragma unroll
    for (int k = 0; k < 4; ++k) {
        v[k].x = exp2f((v[k].x - m) * C);
        v[k].y = exp2f((v[k].y - m) * C);
        v[k].z = exp2f((v[k].z - m) * C);
        v[k].w = exp2f((v[k].w - m) * C);
        s += (v[k].x + v[k].y) + (v[k].z + v[k].w);
    }
#pragma unroll
    for (int d = 32; d >= 1; d >>= 1) s += __shfl_down(s, d);
    if (lane == 0) sred2[wid] = s;
    __syncthreads();
    s = (sred2[0] + sred2[1]) + (sred2[2] + sred2[3]);
    float inv = 1.0f / s;
#pragma unroll
    for (int k = 0; k < 4; ++k) {
        union { __half h[4]; uint2 u; } o;
        o.h[0] = __float2half(v[k].x * inv);
        o.h[1] = __float2half(v[k].y * inv);
        o.h[2] = __float2half(v[k].z * inv);
        o.h[3] = __float2half(v[k].w * inv);
        ((uint2*)dst)[t + 256 * k] = o.u;
    }
}

// ---------------- S-partial: ST[j][i] = sum_v min(ps[i,v], pt[j,v])  ----------
// W = 2 - 2*S. Tile: 128 i x 64 j per block, 8i x 4j per thread.
// grid (8,16,4): x = i-tile, y = j-tile, z = v-split (1024 halfs each).
#define TI 128
#define TJ 64
#define LSTRH 72  // f16 row stride (144 B): 2-way bank aliasing -> free (m136)

__global__ __launch_bounds__(256) void cdist_kernel(const __half* __restrict__ psh,
                                                    const __half* __restrict__ pth,
                                                    float* __restrict__ spart) {
    __shared__ __half sP[2][TI * LSTRH];   // 36,864 B
    __shared__ __half sQ[2][TJ * LSTRH];   // 18,432 B   (total 55.3 KB < 64 KB)
    const int bi = blockIdx.x;
    const int bj = blockIdx.y;
    const int bv = blockIdx.z;
    const int t = threadIdx.x;
    const int cl = t & 15;   // i-lane (0..15)
    const int rl = t >> 4;   // j-lane (0..15)
    const __half* psb = psh + ((size_t)bi * TI) * VSZ + bv * 1024;
    const __half* ptb = pth + ((size_t)bj * TJ) * VSZ + bv * 1024;

    // staging map: P needs 128 rows x 8 float4 = 1024 f4 -> 4/thread;
    //              Q needs  64 rows x 8 float4 =  512 f4 -> 2/thread.
    int prow[4], pcol[4], qrow[2], qcol[2];
#pragma unroll
    for (int k = 0; k < 4; ++k) {
        int g = t + 256 * k;
        prow[k] = g >> 3;
        pcol[k] = (g & 7) * 8;
    }
#pragma unroll
    for (int k = 0; k < 2; ++k) {
        int g = t + 256 * k;
        qrow[k] = g >> 3;
        qcol[k] = (g & 7) * 8;
    }

    float acc[8][4];
#pragma unroll
    for (int u = 0; u < 8; ++u)
#pragma unroll
        for (int w = 0; w < 4; ++w) acc[u][w] = 0.f;

    // prologue: stage tile 0 into buf 0
#pragma unroll
    for (int k = 0; k < 4; ++k) {
        float4 r = *(const float4*)(psb + (size_t)prow[k] * VSZ + pcol[k]);
        *(float4*)(&sP[0][prow[k] * LSTRH + pcol[k]]) = r;
    }
#pragma unroll
    for (int k = 0; k < 2; ++k) {
        float4 r = *(const float4*)(ptb + (size_t)qrow[k] * VSZ + qcol[k]);
        *(float4*)(&sQ[0][qrow[k] * LSTRH + qcol[k]]) = r;
    }
    __syncthreads();

    for (int kt = 0; kt < 16; ++kt) {
        const int cur = kt & 1;
        float4 rp[4], rq[2];
        if (kt < 15) {  // prefetch tile kt+1 (64 halfs further along v)
            const int off = (kt + 1) * 64;
#pragma unroll
            for (int k = 0; k < 4; ++k)
                rp[k] = *(const float4*)(psb + (size_t)prow[k] * VSZ + off + pcol[k]);
#pragma unroll
            for (int k = 0; k < 2; ++k)
                rq[k] = *(const float4*)(ptb + (size_t)qrow[k] * VSZ + off + qcol[k]);
        }
        const __half* pbase = sP[cur] + cl * LSTRH;
        const __half* qbase = sQ[cur] + rl * LSTRH;
#pragma unroll
        for (int vv = 0; vv < 8; ++vv) {
            F4H p[8], q[4];
#pragma unroll
            for (int u = 0; u < 8; ++u)
                p[u].f = *(const float4*)(pbase + u * 16 * LSTRH + vv * 8);
#pragma unroll
            for (int w = 0; w < 4; ++w)
                q[w].f = *(const float4*)(qbase + w * 16 * LSTRH + vv * 8);
#pragma unroll
            for (int u = 0; u < 8; ++u)
#pragma unroll
                for (int w = 0; w < 4; ++w) {
                    h2 m0 = H2MIN(p[u].h[0], q[w].h[0]);
                    h2 m1 = H2MIN(p[u].h[1], q[w].h[1]);
                    h2 m2 = H2MIN(p[u].h[2], q[w].h[2]);
                    h2 m3 = H2MIN(p[u].h[3], q[w].h[3]);
#if defined(__has_builtin) && __has_builtin(__builtin_amdgcn_fdot2)
                    const h2 ones = {(_Float16)1.0f, (_Float16)1.0f};
                    acc[u][w] = __builtin_amdgcn_fdot2(m0, ones, acc[u][w], false);
                    acc[u][w] = __builtin_amdgcn_fdot2(m1, ones, acc[u][w], false);
                    acc[u][w] = __builtin_amdgcn_fdot2(m2, ones, acc[u][w], false);
                    acc[u][w] = __builtin_amdgcn_fdot2(m3, ones, acc[u][w], false);
#else
                    // pk_add_f16 tree (values ~1e-3: f16 partial-sum err ~1e-5)
                    h2 s01 = m0 + m1;
                    h2 s23 = m2 + m3;
                    h2 sm  = s01 + s23;
                    acc[u][w] += (float)sm[0] + (float)sm[1];
#endif
                }
        }
        if (kt < 15) {  // write tile kt+1 into the other buffer
            const int nxt = cur ^ 1;
#pragma unroll
            for (int k = 0; k < 4; ++k)
                *(float4*)(&sP[nxt][prow[k] * LSTRH + pcol[k]]) = rp[k];
#pragma unroll
            for (int k = 0; k < 2; ++k)
                *(float4*)(&sQ[nxt][qrow[k] * LSTRH + qcol[k]]) = rq[k];
        }
        __syncthreads();
    }

    float* outp = spart + (size_t)bv * (BSZ * BSZ);
#pragma unroll
    for (int w = 0; w < 4; ++w) {
        int jr = bj * TJ + rl + 16 * w;
#pragma unroll
        for (int u = 0; u < 8; ++u) {
            int ic = bi * TI + cl + 16 * u;
            outp[(size_t)jr * BSZ + ic] = acc[u][w];
        }
    }
}

// ------- combine v-partials: W = 2 - 2*S, K = exp(-W/eps); also init barrier --
__global__ __launch_bounds__(256) void combine_kernel(const float* __restrict__ spart,
                                                      float* __restrict__ wt,
                                                      float* __restrict__ kt,
                                                      unsigned* __restrict__ bar) {
    if (blockIdx.x == 0 && threadIdx.x == 0) { bar[0] = 0u; bar[1] = 0u; }
    int idx = blockIdx.x * 256 + threadIdx.x;  // over B*B/4 float4s
    const float4* p0 = (const float4*)spart;
    const int Q = (BSZ * BSZ) / 4;
    float4 a = p0[idx], b = p0[idx + Q], c = p0[idx + 2 * Q], d = p0[idx + 3 * Q];
    float4 w;
    w.x = 2.0f - 2.0f * ((a.x + b.x) + (c.x + d.x));
    w.y = 2.0f - 2.0f * ((a.y + b.y) + (c.y + d.y));
    w.z = 2.0f - 2.0f * ((a.z + b.z) + (c.z + d.z));
    w.w = 2.0f - 2.0f * ((a.w + b.w) + (c.w + d.w));
    ((float4*)wt)[idx] = w;
    const float CE = -14.426950408889634f;  // -log2(e)/eps, eps=0.1
    float4 k;
    k.x = exp2f(w.x * CE);
    k.y = exp2f(w.y * CE);
    k.z = exp2f(w.z * CE);
    k.w = exp2f(w.w * CE);
    ((float4*)kt)[idx] = k;
}

// ------- grid barrier: RELAXED polling (no per-poll cache inv), thread-0 fences
__device__ inline void grid_barrier(unsigned* bar) {
    __syncthreads();
    if (threadIdx.x == 0) {
        unsigned g = __hip_atomic_load(&bar[1], __ATOMIC_RELAXED, __HIP_MEMORY_SCOPE_AGENT);
        unsigned old = __hip_atomic_fetch_add(&bar[0], 1u, __ATOMIC_ACQ_REL, __HIP_MEMORY_SCOPE_AGENT);
        if (old == NBLK - 1) {
            __hip_atomic_store(&bar[0], 0u, __ATOMIC_RELAXED, __HIP_MEMORY_SCOPE_AGENT);
            __hip_atomic_store(&bar[1], g + 1u, __ATOMIC_RELEASE, __HIP_MEMORY_SCOPE_AGENT);
        } else {
            while (__hip_atomic_load(&bar[1], __ATOMIC_RELAXED, __HIP_MEMORY_SCOPE_AGENT) == g)
                __builtin_amdgcn_s_sleep(2);
            (void)__hip_atomic_load(&bar[1], __ATOMIC_ACQUIRE, __HIP_MEMORY_SCOPE_AGENT);
        }
    }
    __syncthreads();
}

// ---------------- Sinkhorn: a = 1/(K b); b = 1/(K^T a), 20 iters + final sum --
__global__ __launch_bounds__(256) void sinkhorn_kernel(const float* __restrict__ KT,
                                                       const float* __restrict__ WT,
                                                       float* __restrict__ cpart,
                                                       float* __restrict__ outpart,
                                                       float* __restrict__ out,
                                                       unsigned* __restrict__ bar) {
    __shared__ __align__(16) float k_lds[16 * KPAD];
    __shared__ __align__(16) float a_sh[BSZ];
    __shared__ float b_sh[16];
    __shared__ float red[16];
    const int z = blockIdx.x;
    const int t = threadIdx.x;
    const int j0 = z * 16;
#pragma unroll 4
    for (int r = 0; r < 16; ++r) {
        float4 v = ((const float4*)(KT + (size_t)(j0 + r) * BSZ))[t];
        *(float4*)(&k_lds[r * KPAD + t * 4]) = v;
    }
    if (t < 16) b_sh[t] = 1.0f;
    __syncthreads();
    const int jj = t >> 4;
    const int il = t & 15;
    for (int it = 0; it < 20; ++it) {
        float4* cur = (float4*)(cpart + (size_t)(it & 1) * (NBLK * BSZ) + (size_t)z * BSZ);
        float4 s = {0.f, 0.f, 0.f, 0.f};
#pragma unroll
        for (int q = 0; q < 16; ++q) {
            float4 kv = *(const float4*)(&k_lds[q * KPAD + t * 4]);
            float bb = b_sh[q];
            s.x += kv.x * bb; s.y += kv.y * bb; s.z += kv.z * bb; s.w += kv.w * bb;
        }
        cur[t] = s;
        grid_barrier(bar);
        const float4* curAll = (const float4*)(cpart + (size_t)(it & 1) * (NBLK * BSZ));
        float4 c = {0.f, 0.f, 0.f, 0.f};
        for (int zz = 0; zz < NBLK; ++zz) {
            float4 v = curAll[zz * 256 + t];
            c.x += v.x; c.y += v.y; c.z += v.z; c.w += v.w;
        }
        float4 ar;
        ar.x = 1.0f / c.x; ar.y = 1.0f / c.y; ar.z = 1.0f / c.z; ar.w = 1.0f / c.w;
        ((float4*)a_sh)[t] = ar;
        __syncthreads();
        float sb = 0.f;
#pragma unroll
        for (int m2 = 0; m2 < 16; ++m2) {
            float4 kv = *(const float4*)(&k_lds[jj * KPAD + (il + 16 * m2) * 4]);
            float4 av = ((const float4*)a_sh)[il + 16 * m2];
            sb += (kv.x * av.x + kv.y * av.y) + (kv.z * av.z + kv.w * av.w);
        }
#pragma unroll
        for (int d = 8; d >= 1; d >>= 1) sb += __shfl_down(sb, d, 16);
        if (il == 0) b_sh[jj] = 1.0f / sb;
        __syncthreads();
    }
    {
        const float4* wrow = (const float4*)(WT + (size_t)(j0 + jj) * BSZ);
        float sb = 0.f;
#pragma unroll 4
        for (int m2 = 0; m2 < 16; ++m2) {
            float4 kv = *(const float4*)(&k_lds[jj * KPAD + (il + 16 * m2) * 4]);
            float4 wv = wrow[il + 16 * m2];
            float4 av = ((const float4*)a_sh)[il + 16 * m2];
            sb += (av.x * kv.x * wv.x + av.y * kv.y * wv.y) +
                  (av.z * kv.z * wv.z + av.w * kv.w * wv.w);
        }
#pragma unroll
        for (int d = 8; d >= 1; d >>= 1) sb += __shfl_down(sb, d, 16);
        if (il == 0) red[jj] = sb * b_sh[jj];
        __syncthreads();
        if (t == 0) {
            float ss = 0.f;
#pragma unroll
            for (int q = 0; q < 16; ++q) ss += red[q];
            outpart[z] = ss;
        }
    }
    grid_barrier(bar);
    if (z == 0 && t == 0) {
        float ss = 0.f;
        for (int q = 0; q < NBLK; ++q) ss += outpart[q];
        out[0] = 0.001f * ss;
    }
}

extern "C" void kernel_launch(void* const* d_in, const int* in_sizes, int n_in,
                              void* d_out, int out_size, void* d_ws, size_t ws_size,
                              hipStream_t stream) {
    const float* ys = (const float*)d_in[0];
    const float* yt = (const float*)d_in[1];
    float* ws = (float*)d_ws;
    __half* psh    = (__half*)ws;                          // 2M floats
    __half* pth    = (__half*)(ws + 2ull * 1024 * 1024);   // 2M floats
    float* spart   = ws + 4ull * 1024 * 1024;              // 4 x 1M
    float* wt      = spart + 4ull * BSZ * BSZ;             // 1M
    float* kt      = wt + (size_t)BSZ * BSZ;               // 1M
    float* cpart   = kt + (size_t)BSZ * BSZ;               // 2*64*1024
    float* outpart = cpart + 2ull * NBLK * BSZ;            // 64
    unsigned* bar  = (unsigned*)(outpart + 96);            // own 128B line
    float* outp    = (float*)d_out;

    softmax_kernel<<<dim3(2 * BSZ), dim3(256), 0, stream>>>(ys, yt, psh, pth);
    cdist_kernel<<<dim3(8, 16, 4), dim3(256), 0, stream>>>(psh, pth, spart);
    combine_kernel<<<dim3((BSZ * BSZ / 4) / 256), dim3(256), 0, stream>>>(spart, wt, kt, bar);

    void* args[] = {(void*)&kt, (void*)&wt, (void*)&cpart, (void*)&outpart, (void*)&outp, (void*)&bar};
    hipLaunchCooperativeKernel((void*)sinkhorn_kernel, dim3(NBLK), dim3(256), args, 0, stream);
}